// Round 12
// baseline (26.940 us; speedup 1.0000x reference)
//
#include <hip/hip_runtime.h>

#define BLOCK 256
#define NPT 8
#define CHUNK (BLOCK * NPT)   // 2048 nodes per block
#define TBL 64                // LDS graph slots per block (data max ~18 used)

__device__ __forceinline__ int padw(int w) { return w + (w >> 5); }  // +1 word per 32

// Single fused kernel (R11 skeleton, R12 coalesced staging).
// Block b covers nodes [s,e) and exclusively owns graphs (batch[s-1], batch[e-1]].
// Collapsed model (proven R7-R11): per graph we only need (Σ t*p, Σ t, cnt),
// t = embed[z]^4, transformed once in the epilogue.
__global__ __launch_bounds__(BLOCK) void e3nn_one(
    const int* __restrict__ z, const float* __restrict__ pos,
    const int* __restrict__ batch, const float* __restrict__ embed,
    const float* __restrict__ lin_w, const float* __restrict__ lin_b,
    const float* __restrict__ tp1_w, const float* __restrict__ tp2_w,
    const float* __restrict__ tp3_w, const float* __restrict__ gate_w,
    const float* __restrict__ fc_w, const float* __restrict__ fc_b,
    float* __restrict__ out, int n, int G)
{
    __shared__ float t4s[100];
    __shared__ float acc[TBL * 5];     // (sx,sy,sz,st,cnt) per owned graph slot
    __shared__ float stage[6336];      // 6144 data + 192 pad words (25.3 KB)

    const int tid  = threadIdx.x;
    const int lane = tid & 63;
    const int b    = blockIdx.x;
    const int s    = b * CHUNK;
    const int e    = min(s + CHUNK, n);

    const int prev   = (s == 0) ? -1 : batch[s - 1];
    const int mylast = batch[e - 1];

    float px[NPT], py[NPT], pz[NPT], tv[NPT];
    int bi[NPT];

    if (e - s == CHUNK) {
        // ---- phase 1: issue ALL global loads lane-coalesced (16B stride) ----
        const float4* posf4 = (const float4*)pos;
        const int4*   z4p   = (const int4*)z;
        const int4*   b4p   = (const int4*)batch;
        const int F0 = b * 1536;   // block's first pos-float4
        const int Z0 = b * 512;    // block's first z/batch-int4

        float4 pv[6];
#pragma unroll
        for (int j = 0; j < 6; ++j) pv[j] = posf4[F0 + tid + 256 * j];
        int4 zv0 = z4p[Z0 + tid], zv1 = z4p[Z0 + tid + 256];
        int4 bv0 = b4p[Z0 + tid], bv1 = b4p[Z0 + tid + 256];

        if (tid < 100) { float v = embed[tid]; float v2 = v * v; t4s[tid] = v2 * v2; }
        for (int i2 = tid; i2 < TBL * 5; i2 += BLOCK) acc[i2] = 0.f;

        // pos -> padded LDS (w=4F: all 4 words in same pad group)
#pragma unroll
        for (int j = 0; j < 6; ++j) {
            int p0 = padw(4 * (tid + 256 * j));
            stage[p0    ] = pv[j].x;
            stage[p0 + 1] = pv[j].y;
            stage[p0 + 2] = pv[j].z;
            stage[p0 + 3] = pv[j].w;
        }
        __syncthreads();

        // ---- phase 2: transpose-read own 8 nodes' pos (≤2-way banks) ----
#pragma unroll
        for (int k = 0; k < NPT; ++k) {
            int w = 24 * tid + 3 * k;
            px[k] = stage[padw(w)];
            py[k] = stage[padw(w + 1)];
            pz[k] = stage[padw(w + 2)];
        }
        __syncthreads();

        // ---- phase 3: stage t4[z] (mapped at write) and batch ----
        {
            int p0 = padw(4 * tid);
            stage[p0    ] = t4s[zv0.x];
            stage[p0 + 1] = t4s[zv0.y];
            stage[p0 + 2] = t4s[zv0.z];
            stage[p0 + 3] = t4s[zv0.w];
            int p1 = padw(4 * (tid + 256));
            stage[p1    ] = t4s[zv1.x];
            stage[p1 + 1] = t4s[zv1.y];
            stage[p1 + 2] = t4s[zv1.z];
            stage[p1 + 3] = t4s[zv1.w];
            int q0 = 2112 + p0;
            stage[q0    ] = __int_as_float(bv0.x);
            stage[q0 + 1] = __int_as_float(bv0.y);
            stage[q0 + 2] = __int_as_float(bv0.z);
            stage[q0 + 3] = __int_as_float(bv0.w);
            int q1 = 2112 + p1;
            stage[q1    ] = __int_as_float(bv1.x);
            stage[q1 + 1] = __int_as_float(bv1.y);
            stage[q1 + 2] = __int_as_float(bv1.z);
            stage[q1 + 3] = __int_as_float(bv1.w);
        }
        __syncthreads();

#pragma unroll
        for (int k = 0; k < NPT; ++k) {
            int w = 8 * tid + k;
            tv[k] = stage[padw(w)];
            bi[k] = __float_as_int(stage[2112 + padw(w)]);
        }
    } else {
        // ---- tail fallback: direct guarded loads (block-uniform branch) ----
        if (tid < 100) { float v = embed[tid]; float v2 = v * v; t4s[tid] = v2 * v2; }
        for (int i2 = tid; i2 < TBL * 5; i2 += BLOCK) acc[i2] = 0.f;
        __syncthreads();
        long long i0 = (long long)s + (long long)tid * NPT;
#pragma unroll
        for (int k = 0; k < NPT; ++k) {
            long long i = i0 + k;
            if (i < (long long)e) {
                px[k] = pos[i*3]; py[k] = pos[i*3+1]; pz[k] = pos[i*3+2];
                tv[k] = t4s[z[i]]; bi[k] = batch[i];
            } else { px[k]=0.f; py[k]=0.f; pz[k]=0.f; tv[k]=0.f; bi[k] = -1; }
        }
    }

    // flush a run into the block's LDS table; head graph (slot<0, owned by the
    // previous block, which spill-reads our nodes) is dropped.
    auto lflush = [&](int g, float ax, float ay, float az, float at, float ac) {
        int slot = g - prev - 1;
        if (slot >= 0 && slot < TBL) {
            atomicAdd(&acc[slot*5+0], ax);
            atomicAdd(&acc[slot*5+1], ay);
            atomicAdd(&acc[slot*5+2], az);
            atomicAdd(&acc[slot*5+3], at);
            atomicAdd(&acc[slot*5+4], ac);
        }
    };

    // ---- per-thread run compression (slim payload) ----
    float ax=0.f, ay=0.f, az=0.f, at=0.f, ac=0.f;
    int rb = -1;
#pragma unroll
    for (int k = 0; k < NPT; ++k) {
        if (bi[k] < 0) continue;
        float t = tv[k];
        if (bi[k] == rb) {
            ax += t*px[k]; ay += t*py[k]; az += t*pz[k]; at += t; ac += 1.f;
        } else {
            if (rb >= 0) lflush(rb, ax, ay, az, at, ac);
            rb = bi[k];
            ax = t*px[k]; ay = t*py[k]; az = t*pz[k]; at = t; ac = 1.f;
        }
    }

    // ---- wave-level segmented suffix reduce over each lane's last run ----
#pragma unroll
    for (int off = 1; off < 64; off <<= 1) {
        int   ob = __shfl_down(rb, off);
        float qx = __shfl_down(ax, off);
        float qy = __shfl_down(ay, off);
        float qz = __shfl_down(az, off);
        float qt = __shfl_down(at, off);
        float qc = __shfl_down(ac, off);
        if ((lane + off) < 64 && ob == rb) {
            ax += qx; ay += qy; az += qz; at += qt; ac += qc;
        }
    }
    {
        int pb = __shfl_up(rb, 1);
        bool head = (lane == 0) || (pb != rb);
        if (rb >= 0 && head) lflush(rb, ax, ay, az, at, ac);
    }

    // ---- spill scan: finish owned boundary graph `mylast` past e ----
    if ((tid >> 6) == 3 && e < n && mylast > prev) {
        float sx=0.f, sy=0.f, sz=0.f, st=0.f, sc=0.f;
        int base = e;
        for (;;) {
            bool allok = true;
#pragma unroll
            for (int k = 0; k < 4; ++k) {
                int idx = base + lane * 4 + k;
                bool ok = (idx < n) && (batch[idx] == mylast);
                if (ok) {
                    float t = t4s[z[idx]];
                    sx += t*pos[3*idx]; sy += t*pos[3*idx+1]; sz += t*pos[3*idx+2];
                    st += t; sc += 1.f;
                } else allok = false;
            }
            unsigned long long m = __ballot(allok);
            if (m != ~0ULL) break;
            base += 256;
        }
#pragma unroll
        for (int off = 1; off < 64; off <<= 1) {
            sx += __shfl_xor(sx, off);
            sy += __shfl_xor(sy, off);
            sz += __shfl_xor(sz, off);
            st += __shfl_xor(st, off);
            sc += __shfl_xor(sc, off);
        }
        if (lane == 0) {
            int slot = mylast - prev - 1;
            if (slot < TBL) {
                atomicAdd(&acc[slot*5+0], sx);
                atomicAdd(&acc[slot*5+1], sy);
                atomicAdd(&acc[slot*5+2], sz);
                atomicAdd(&acc[slot*5+3], st);
                atomicAdd(&acc[slot*5+4], sc);
            }
        }
    }

    __syncthreads();

    // ---- epilogue: transform + plain-store owned graphs (prev, gend] ----
    const float C01 = 0.57735026918962576f;   // 1/sqrt(3)
    const float PW2 = 1.2247448713915890f;    // sqrt(1.5)
    const float k1  = (tp1_w[0] + tp1_w[1]) * C01;
    const float C   = k1 * (PW2*tp2_w[0]*C01) * (PW2*tp3_w[0]*C01) * (PW2*gate_w[0]*C01);

    float lw[9], fw[9], lbv[3], fbv[3];
#pragma unroll
    for (int i = 0; i < 9; ++i) { lw[i] = lin_w[i]; fw[i] = fc_w[i]; }
#pragma unroll
    for (int i = 0; i < 3; ++i) { lbv[i] = lin_b[i]; fbv[i] = fc_b[i]; }

    float W[9], u[3];
#pragma unroll
    for (int r = 0; r < 3; ++r) {
#pragma unroll
        for (int cc = 0; cc < 3; ++cc)
            W[r*3+cc] = fw[r*3+0]*lw[0*3+cc] + fw[r*3+1]*lw[1*3+cc] + fw[r*3+2]*lw[2*3+cc];
        u[r] = fw[r*3+0]*lbv[0] + fw[r*3+1]*lbv[1] + fw[r*3+2]*lbv[2];
    }

    const int gend  = (e == n) ? (G - 1) : mylast;
    const int count = gend - prev;

    for (int o = tid; o < count; o += BLOCK) {
        float vx=0.f, vy=0.f, vz=0.f, vt=0.f, vc=0.f;
        if (o < TBL) {
            vx = acc[o*5+0]; vy = acc[o*5+1]; vz = acc[o*5+2];
            vt = acc[o*5+3]; vc = acc[o*5+4];
        }
        int g = prev + 1 + o;
        out[3*g+0] = C * (W[0]*vx + W[1]*vy + W[2]*vz + vt*u[0]) + vc*fbv[0];
        out[3*g+1] = C * (W[3]*vx + W[4]*vy + W[5]*vz + vt*u[1]) + vc*fbv[1];
        out[3*g+2] = C * (W[6]*vx + W[7]*vy + W[8]*vz + vt*u[2]) + vc*fbv[2];
    }
}

extern "C" void kernel_launch(void* const* d_in, const int* in_sizes, int n_in,
                              void* d_out, int out_size, void* d_ws, size_t ws_size,
                              hipStream_t stream) {
    const int*   z     = (const int*)  d_in[0];
    const float* pos   = (const float*)d_in[1];
    const int*   batch = (const int*)  d_in[2];
    const float* embed = (const float*)d_in[3];
    const float* lin_w = (const float*)d_in[4];
    const float* lin_b = (const float*)d_in[5];
    const float* tp1_w = (const float*)d_in[6];
    const float* tp2_w = (const float*)d_in[7];
    const float* tp3_w = (const float*)d_in[8];
    const float* gate_w= (const float*)d_in[9];
    const float* fc_w  = (const float*)d_in[10];
    const float* fc_b  = (const float*)d_in[11];
    float* out = (float*)d_out;

    int n = in_sizes[0];
    int G = out_size / 3;

    int nblocks = (n + CHUNK - 1) / CHUNK;   // 2048
    e3nn_one<<<nblocks, BLOCK, 0, stream>>>(
        z, pos, batch, embed, lin_w, lin_b,
        tp1_w, tp2_w, tp3_w, gate_w, fc_w, fc_b, out, n, G);
}

// Round 13
// 22.626 us; speedup vs baseline: 1.1907x; 1.1907x over previous
//
#include <hip/hip_runtime.h>

#define BLOCK 256
#define NPT 16
#define CHUNK (BLOCK * NPT)   // 4096 nodes per block
#define TBL 96                // LDS graph slots per block (span ~33±6, +11σ safe)

// Single fused kernel (R11 skeleton, NPT=16).
// Block b covers nodes [s,e) and exclusively owns graphs (batch[s-1], batch[e-1]].
// Collapsed model (proven R7-R12): per graph we only need (Σ t*p, Σ t, cnt),
// t = embed[z]^4, transformed once in the epilogue:
//   out[g] = C*(W@Σtp + Σt*u) + cnt*fc_b,  W=fc_w@lin_w, u=fc_w@lin_b.
__global__ __launch_bounds__(BLOCK, 2) void e3nn_one(
    const int* __restrict__ z, const float* __restrict__ pos,
    const int* __restrict__ batch, const float* __restrict__ embed,
    const float* __restrict__ lin_w, const float* __restrict__ lin_b,
    const float* __restrict__ tp1_w, const float* __restrict__ tp2_w,
    const float* __restrict__ tp3_w, const float* __restrict__ gate_w,
    const float* __restrict__ fc_w, const float* __restrict__ fc_b,
    float* __restrict__ out, int n, int G)
{
    __shared__ float t4s[100];
    __shared__ float acc[TBL * 5];   // (sx,sy,sz,st,cnt) per owned graph slot

    const int tid  = threadIdx.x;
    const int lane = tid & 63;
    const int b    = blockIdx.x;
    const int s    = b * CHUNK;
    const int e    = min(s + CHUNK, n);

    if (tid < 100) { float v = embed[tid]; float v2 = v * v; t4s[tid] = v2 * v2; }
    for (int i = tid; i < TBL * 5; i += BLOCK) acc[i] = 0.f;
    __syncthreads();

    const int prev   = (s == 0) ? -1 : batch[s - 1];
    const int mylast = batch[e - 1];

    // ---- load 16 nodes/thread (R11-proven direct vectorized path) ----
    const long long i0 = (long long)s + (long long)tid * NPT;
    float pf[NPT * 3];
    int   zz[NPT], bi[NPT];

    if (i0 + NPT <= (long long)n) {
        const float4* p4 = (const float4*)(pos + i0 * 3);
#pragma unroll
        for (int j = 0; j < NPT * 3 / 4; ++j)
            *((float4*)pf + j) = p4[j];
        const int4* z4 = (const int4*)(z + i0);
#pragma unroll
        for (int j = 0; j < NPT / 4; ++j)
            *((int4*)zz + j) = z4[j];
        const int4* b4 = (const int4*)(batch + i0);
#pragma unroll
        for (int j = 0; j < NPT / 4; ++j)
            *((int4*)bi + j) = b4[j];
    } else {
#pragma unroll
        for (int k = 0; k < NPT; ++k) {
            long long i = i0 + k;
            if (i < (long long)n) {
                pf[3*k] = pos[i*3]; pf[3*k+1] = pos[i*3+1]; pf[3*k+2] = pos[i*3+2];
                zz[k] = z[i]; bi[k] = batch[i];
            } else { pf[3*k]=0.f; pf[3*k+1]=0.f; pf[3*k+2]=0.f; zz[k]=0; bi[k]=-1; }
        }
    }

    // flush a run into the block's LDS table; head graph (slot<0, owned by the
    // previous block, which spill-reads our nodes) is dropped.
    auto lflush = [&](int g, float ax, float ay, float az, float at, float ac) {
        int slot = g - prev - 1;
        if (slot >= 0 && slot < TBL) {
            atomicAdd(&acc[slot*5+0], ax);
            atomicAdd(&acc[slot*5+1], ay);
            atomicAdd(&acc[slot*5+2], az);
            atomicAdd(&acc[slot*5+3], at);
            atomicAdd(&acc[slot*5+4], ac);
        }
    };

    // ---- per-thread run compression (slim payload) ----
    float ax=0.f, ay=0.f, az=0.f, at=0.f, ac=0.f;
    int rb = -1;
#pragma unroll
    for (int k = 0; k < NPT; ++k) {
        if (bi[k] < 0) continue;
        float t = t4s[zz[k]];
        if (bi[k] == rb) {
            ax += t*pf[3*k]; ay += t*pf[3*k+1]; az += t*pf[3*k+2]; at += t; ac += 1.f;
        } else {
            if (rb >= 0) lflush(rb, ax, ay, az, at, ac);
            rb = bi[k];
            ax = t*pf[3*k]; ay = t*pf[3*k+1]; az = t*pf[3*k+2]; at = t; ac = 1.f;
        }
    }

    // ---- wave-level segmented suffix reduce over each lane's last run ----
#pragma unroll
    for (int off = 1; off < 64; off <<= 1) {
        int   ob = __shfl_down(rb, off);
        float qx = __shfl_down(ax, off);
        float qy = __shfl_down(ay, off);
        float qz = __shfl_down(az, off);
        float qt = __shfl_down(at, off);
        float qc = __shfl_down(ac, off);
        if ((lane + off) < 64 && ob == rb) {
            ax += qx; ay += qy; az += qz; at += qt; ac += qc;
        }
    }
    {
        int pb = __shfl_up(rb, 1);
        bool head = (lane == 0) || (pb != rb);
        if (rb >= 0 && head) lflush(rb, ax, ay, az, at, ac);
    }

    // ---- spill scan: finish owned boundary graph `mylast` past e ----
    // (sorted keys: its remaining nodes are contiguous from e). Skipped when
    // mylast==prev (graph started earlier; previous owner scans through us).
    if ((tid >> 6) == 3 && e < n && mylast > prev) {
        float sx=0.f, sy=0.f, sz=0.f, st=0.f, sc=0.f;
        int base = e;
        for (;;) {
            bool allok = true;
#pragma unroll
            for (int k = 0; k < 4; ++k) {
                int idx = base + lane * 4 + k;
                bool ok = (idx < n) && (batch[idx] == mylast);
                if (ok) {
                    float t = t4s[z[idx]];
                    sx += t*pos[3*idx]; sy += t*pos[3*idx+1]; sz += t*pos[3*idx+2];
                    st += t; sc += 1.f;
                } else allok = false;
            }
            unsigned long long m = __ballot(allok);
            if (m != ~0ULL) break;     // some lane saw end-of-graph (or n)
            base += 256;               // graph continues past the window
        }
#pragma unroll
        for (int off = 1; off < 64; off <<= 1) {
            sx += __shfl_xor(sx, off);
            sy += __shfl_xor(sy, off);
            sz += __shfl_xor(sz, off);
            st += __shfl_xor(st, off);
            sc += __shfl_xor(sc, off);
        }
        if (lane == 0) {
            int slot = mylast - prev - 1;      // >= 0 here
            if (slot < TBL) {
                atomicAdd(&acc[slot*5+0], sx);
                atomicAdd(&acc[slot*5+1], sy);
                atomicAdd(&acc[slot*5+2], sz);
                atomicAdd(&acc[slot*5+3], st);
                atomicAdd(&acc[slot*5+4], sc);
            }
        }
    }

    __syncthreads();

    // ---- epilogue: transform + plain-store owned graphs (prev, gend] ----
    const float C01 = 0.57735026918962576f;   // 1/sqrt(3)
    const float PW2 = 1.2247448713915890f;    // sqrt(1.5)
    const float k1  = (tp1_w[0] + tp1_w[1]) * C01;
    const float C   = k1 * (PW2*tp2_w[0]*C01) * (PW2*tp3_w[0]*C01) * (PW2*gate_w[0]*C01);

    float lw[9], fw[9], lbv[3], fbv[3];
#pragma unroll
    for (int i = 0; i < 9; ++i) { lw[i] = lin_w[i]; fw[i] = fc_w[i]; }
#pragma unroll
    for (int i = 0; i < 3; ++i) { lbv[i] = lin_b[i]; fbv[i] = fc_b[i]; }

    float W[9], u[3];
#pragma unroll
    for (int r = 0; r < 3; ++r) {
#pragma unroll
        for (int cc = 0; cc < 3; ++cc)
            W[r*3+cc] = fw[r*3+0]*lw[0*3+cc] + fw[r*3+1]*lw[1*3+cc] + fw[r*3+2]*lw[2*3+cc];
        u[r] = fw[r*3+0]*lbv[0] + fw[r*3+1]*lbv[1] + fw[r*3+2]*lbv[2];
    }

    const int gend  = (e == n) ? (G - 1) : mylast;  // last block owns trailing empties
    const int count = gend - prev;                  // graphs prev+1 .. gend

    for (int o = tid; o < count; o += BLOCK) {
        float vx=0.f, vy=0.f, vz=0.f, vt=0.f, vc=0.f;
        if (o < TBL) {
            vx = acc[o*5+0]; vy = acc[o*5+1]; vz = acc[o*5+2];
            vt = acc[o*5+3]; vc = acc[o*5+4];
        }
        int g = prev + 1 + o;
        out[3*g+0] = C * (W[0]*vx + W[1]*vy + W[2]*vz + vt*u[0]) + vc*fbv[0];
        out[3*g+1] = C * (W[3]*vx + W[4]*vy + W[5]*vz + vt*u[1]) + vc*fbv[1];
        out[3*g+2] = C * (W[6]*vx + W[7]*vy + W[8]*vz + vt*u[2]) + vc*fbv[2];
    }
}

extern "C" void kernel_launch(void* const* d_in, const int* in_sizes, int n_in,
                              void* d_out, int out_size, void* d_ws, size_t ws_size,
                              hipStream_t stream) {
    const int*   z     = (const int*)  d_in[0];
    const float* pos   = (const float*)d_in[1];
    const int*   batch = (const int*)  d_in[2];
    const float* embed = (const float*)d_in[3];
    const float* lin_w = (const float*)d_in[4];
    const float* lin_b = (const float*)d_in[5];
    const float* tp1_w = (const float*)d_in[6];
    const float* tp2_w = (const float*)d_in[7];
    const float* tp3_w = (const float*)d_in[8];
    const float* gate_w= (const float*)d_in[9];
    const float* fc_w  = (const float*)d_in[10];
    const float* fc_b  = (const float*)d_in[11];
    float* out = (float*)d_out;

    int n = in_sizes[0];
    int G = out_size / 3;

    int nblocks = (n + CHUNK - 1) / CHUNK;   // 1024
    e3nn_one<<<nblocks, BLOCK, 0, stream>>>(
        z, pos, batch, embed, lin_w, lin_b,
        tp1_w, tp2_w, tp3_w, gate_w, fc_w, fc_b, out, n, G);
}